// Round 6
// baseline (421.887 us; speedup 1.0000x reference)
//
#include <hip/hip_runtime.h>
#include <hip/hip_cooperative_groups.h>
#include <math.h>

namespace cg = cooperative_groups;

#define NN 4096
#define DD 256
#define HH 4
#define SPLIT 8
#define NB 512      // grid blocks (all phases)
#define BMG 64      // gemm M-tile
#define BKG 64      // gemm K-tile

typedef short short8 __attribute__((ext_vector_type(8)));
typedef float float4v __attribute__((ext_vector_type(4)));

__device__ __forceinline__ unsigned short f2bf(float f) {
  unsigned u = __float_as_uint(f);
  u += 0x7FFF + ((u >> 16) & 1);   // RNE
  return (unsigned short)(u >> 16);
}
__device__ __forceinline__ unsigned f2bf_pk(float a, float b) {
  unsigned ua = __float_as_uint(a); ua += 0x7FFF + ((ua >> 16) & 1);
  unsigned ub = __float_as_uint(b); ub += 0x7FFF + ((ub >> 16) & 1);
  return __builtin_amdgcn_perm(ub, ua, 0x07060302);
}
__device__ __forceinline__ void gld16(void* lds, const void* gp) {
  __builtin_amdgcn_global_load_lds(
      (const __attribute__((address_space(1))) unsigned int*)gp,
      (__attribute__((address_space(3))) unsigned int*)lds, 16, 0, 0);
}

// ---------------- phase 1: transpose tile (32j x 64d) + scores for 8 nodes ----------------
__device__ void phase1(const float* __restrict__ x, const float* __restrict__ a,
                       float cw, float cb, unsigned short* __restrict__ hbfT,
                       float* __restrict__ s1, float* __restrict__ s2,
                       float* __restrict__ s2e, int bid, char* smem) {
  const int tid = threadIdx.x;
  float (*t)[65] = (float (*)[65])smem;   // 32 x 65 floats = 8.3 KB
  const int j0 = (bid >> 2) * 32, d0 = (bid & 3) * 64;
  {
    const int r = tid >> 4, c4 = tid & 15;
#pragma unroll
    for (int p = 0; p < 2; p++) {
      const int jj = p * 16 + r;
      const float4 v = *(const float4*)(x + (size_t)(j0 + jj) * DD + d0 + c4 * 4);
      t[jj][c4 * 4 + 0] = v.x * cw + cb;
      t[jj][c4 * 4 + 1] = v.y * cw + cb;
      t[jj][c4 * 4 + 2] = v.z * cw + cb;
      t[jj][c4 * 4 + 3] = v.w * cw + cb;
    }
  }
  __syncthreads();
  {
    const int dgrp = tid >> 3, jc = (tid & 7) * 4;
#pragma unroll
    for (int p = 0; p < 2; p++) {
      const int dd = p * 32 + dgrp;
      const unsigned l0 = f2bf(t[jc + 0][dd]);
      const unsigned l1 = f2bf(t[jc + 1][dd]);
      const unsigned l2 = f2bf(t[jc + 2][dd]);
      const unsigned l3 = f2bf(t[jc + 3][dd]);
      uint2 val;
      val.x = l0 | (l1 << 16);
      val.y = l2 | (l3 << 16);
      *(uint2*)(hbfT + (size_t)(d0 + dd) * NN + j0 + jc) = val;
    }
  }
  const int lane = tid & 63, wv = tid >> 6;
#pragma unroll
  for (int rr = 0; rr < 2; rr++) {
    const int node = bid * 8 + wv * 2 + rr;
    const float4 xv = *(const float4*)(x + (size_t)node * DD + lane * 4);
    const float h0 = xv.x * cw + cb, h1 = xv.y * cw + cb;
    const float h2 = xv.z * cw + cb, h3 = xv.w * cw + cb;
    float p1[HH], p2[HH];
#pragma unroll
    for (int h = 0; h < HH; h++) {
      const float4 a1 = *(const float4*)(a + h * 512 + lane * 4);
      const float4 a2 = *(const float4*)(a + h * 512 + 256 + lane * 4);
      p1[h] = h0 * a1.x + h1 * a1.y + h2 * a1.z + h3 * a1.w;
      p2[h] = h0 * a2.x + h1 * a2.y + h2 * a2.z + h3 * a2.w;
    }
#pragma unroll
    for (int off = 32; off; off >>= 1) {
#pragma unroll
      for (int h = 0; h < HH; h++) {
        p1[h] += __shfl_xor(p1[h], off);
        p2[h] += __shfl_xor(p2[h], off);
      }
    }
    if (lane == 0) {
#pragma unroll
      for (int h = 0; h < HH; h++) {
        s1[h * NN + node] = p1[h];
        s2[h * NN + node] = p2[h];
        s2e[h * NN + node] = __expf(p2[h]);
      }
    }
  }
}

// ---------------- phase 2: per-head global max of s2 ----------------
__device__ void phase2(const float* __restrict__ s2, float* __restrict__ Mb,
                       int bid, char* smem) {
  if (bid >= HH) return;
  float* red = (float*)smem;
  const int h = bid;
  float m = -1e30f;
  for (int j = threadIdx.x; j < NN; j += 256) m = fmaxf(m, s2[h * NN + j]);
#pragma unroll
  for (int off = 32; off; off >>= 1) m = fmaxf(m, __shfl_xor(m, off));
  const int lane = threadIdx.x & 63, wv = threadIdx.x >> 6;
  if (lane == 0) red[wv] = m;
  __syncthreads();
  if (threadIdx.x == 0)
    Mb[h] = fmaxf(fmaxf(red[0], red[1]), fmaxf(red[2], red[3]));
}

// ---------------- phase 3: fused Z + W (register P, separable exp), 8 rows/block ----------------
__device__ void phase3(const int* __restrict__ adj, const float* __restrict__ s1g,
                       const float* __restrict__ s2e, const float* __restrict__ Mb,
                       unsigned short* __restrict__ Wm, int bid, char* smem) {
  float* red = (float*)smem;    // [4][HH]
  float* sZi = red + 16;        // [HH]
  const int tid = threadIdx.x;
  const int lane = tid & 63, wv = tid >> 6;
  float M[HH];
#pragma unroll
  for (int h = 0; h < HH; h++) M[h] = Mb[h];

#pragma unroll 1
  for (int rr = 0; rr < 8; rr++) {
    const int i = bid + NB * rr;
    float Rp[HH], RpRB[HH], Cc[HH], z[HH];
#pragma unroll
    for (int h = 0; h < HH; h++) {
      const float s1v = s1g[h * NN + i];
      const float t = s1v + M[h];
      const float B = t > 0.f ? t : __expf(t) - 1.f;
      Rp[h] = __expf(s1v);
      RpRB[h] = __expf(s1v - B);
      Cc[h] = __expf(-1.f - B);
      z[h] = 0.f;
    }
    unsigned P[4][HH][2];
    const int4* arow = (const int4*)(adj + (size_t)i * NN);
#pragma unroll
    for (int k = 0; k < 4; k++) {
      const int j4 = tid + k * 256;
      const int4 av = arow[j4];
      const bool m0 = av.x > 0, m1 = av.y > 0, m2 = av.z > 0, m3 = av.w > 0;
#pragma unroll
      for (int h = 0; h < HH; h++) {
        const float4 E = *(const float4*)(s2e + h * NN + j4 * 4);
        float u, p0, p1, p2, p3;
        u = Rp[h] * E.x; p0 = u > 1.f ? RpRB[h] * E.x : Cc[h] * __expf(u);
        u = Rp[h] * E.y; p1 = u > 1.f ? RpRB[h] * E.y : Cc[h] * __expf(u);
        u = Rp[h] * E.z; p2 = u > 1.f ? RpRB[h] * E.z : Cc[h] * __expf(u);
        u = Rp[h] * E.w; p3 = u > 1.f ? RpRB[h] * E.w : Cc[h] * __expf(u);
        p0 = m0 ? p0 : 0.f; p1 = m1 ? p1 : 0.f;
        p2 = m2 ? p2 : 0.f; p3 = m3 ? p3 : 0.f;
        z[h] += (p0 + p1) + (p2 + p3);
        P[k][h][0] = f2bf_pk(p0, p1);
        P[k][h][1] = f2bf_pk(p2, p3);
      }
    }
#pragma unroll
    for (int h = 0; h < HH; h++) {
#pragma unroll
      for (int off = 32; off; off >>= 1) z[h] += __shfl_xor(z[h], off);
    }
    if (lane == 0) {
#pragma unroll
      for (int h = 0; h < HH; h++) red[wv * HH + h] = z[h];
    }
    __syncthreads();
    if (tid < HH) {
      const float zt = red[tid] + red[HH + tid] + red[2 * HH + tid] + red[3 * HH + tid];
      sZi[tid] = zt > 0.f ? 0.25f / zt : 0.f;
    }
    __syncthreads();
    float Zi[HH];
#pragma unroll
    for (int h = 0; h < HH; h++) Zi[h] = sZi[h];

    unsigned* wrow = (unsigned*)(Wm + (size_t)i * NN);
#pragma unroll
    for (int k = 0; k < 4; k++) {
      const int j4 = tid + k * 256;
      float w0 = 0.f, w1 = 0.f, w2 = 0.f, w3 = 0.f;
#pragma unroll
      for (int h = 0; h < HH; h++) {
        const unsigned pa = P[k][h][0];
        const unsigned pb = P[k][h][1];
        w0 += __uint_as_float(pa << 16) * Zi[h];
        w1 += __uint_as_float(pa & 0xffff0000u) * Zi[h];
        w2 += __uint_as_float(pb << 16) * Zi[h];
        w3 += __uint_as_float(pb & 0xffff0000u) * Zi[h];
      }
      wrow[j4 * 2] = f2bf_pk(w0, w1);
      wrow[j4 * 2 + 1] = f2bf_pk(w2, w3);
    }
    __syncthreads();
  }
}

// ---------------- phase 4: MFMA GEMM hp = W @ h, LDS-staged via global_load_lds ----------------
__device__ void phase4(const unsigned short* __restrict__ Wm,
                       const unsigned short* __restrict__ hbfT,
                       float* __restrict__ hp, int useSplit, int bid, char* smem) {
  unsigned short* sA = (unsigned short*)smem;            // 64 x 64 bf16 = 8 KB
  unsigned short* sB = (unsigned short*)(smem + 8192);   // 256 x 64 bf16 = 32 KB
  const int tid = threadIdx.x;
  const int wv = tid >> 6, lane = tid & 63;
  const int m16 = lane & 15, q = lane >> 4;
  const int rb = bid >> 3, sp = bid & 7;
  const int i0 = rb * BMG;
  const int jlo = sp * (NN / SPLIT);
  const int lr = lane >> 3, lc = (lane & 7) * 8;

  float4v acc[4][4];
#pragma unroll
  for (int a = 0; a < 4; a++)
#pragma unroll
    for (int b = 0; b < 4; b++) acc[a][b] = (float4v)0.f;

  for (int kt = 0; kt < (NN / SPLIT) / BKG; kt++) {
    const int j0 = jlo + kt * BKG;
    __syncthreads();
#pragma unroll
    for (int t = 0; t < 2; t++) {
      const int r0 = wv * 16 + t * 8;
      gld16(sA + r0 * BKG, Wm + (size_t)(i0 + r0 + lr) * NN + j0 + lc);
    }
#pragma unroll
    for (int t = 0; t < 8; t++) {
      const int d0 = wv * 64 + t * 8;
      gld16(sB + d0 * BKG, hbfT + (size_t)(d0 + lr) * NN + j0 + lc);
    }
    __syncthreads();
#pragma unroll
    for (int ks = 0; ks < 2; ks++) {
      const int kb = ks * 32 + q * 8;
      short8 aF[4], bF[4];
#pragma unroll
      for (int it = 0; it < 4; it++)
        aF[it] = *(const short8*)(sA + (it * 16 + m16) * BKG + kb);
#pragma unroll
      for (int dt = 0; dt < 4; dt++)
        bF[dt] = *(const short8*)(sB + (wv * 64 + dt * 16 + m16) * BKG + kb);
#pragma unroll
      for (int it = 0; it < 4; it++)
#pragma unroll
        for (int dt = 0; dt < 4; dt++)
          acc[it][dt] = __builtin_amdgcn_mfma_f32_16x16x32_bf16(aF[it], bF[dt], acc[it][dt], 0, 0, 0);
    }
  }

  if (useSplit) {
    float* base = hp + (size_t)sp * NN * DD;
#pragma unroll
    for (int it = 0; it < 4; it++)
#pragma unroll
      for (int dt = 0; dt < 4; dt++) {
        const int d = wv * 64 + dt * 16 + m16;
#pragma unroll
        for (int rg = 0; rg < 4; rg++)
          base[(size_t)(i0 + it * 16 + q * 4 + rg) * DD + d] = acc[it][dt][rg];
      }
  } else {
#pragma unroll
    for (int it = 0; it < 4; it++)
#pragma unroll
      for (int dt = 0; dt < 4; dt++) {
        const int d = wv * 64 + dt * 16 + m16;
#pragma unroll
        for (int rg = 0; rg < 4; rg++)
          atomicAdd(&hp[(size_t)(i0 + it * 16 + q * 4 + rg) * DD + d], acc[it][dt][rg]);
      }
  }
}

// ---------------- phase 5: epilogue, 8 rows/block ----------------
__device__ void phase5(const float* __restrict__ hp, int nsplit,
                       const float* __restrict__ x, float cw, float cb,
                       const float* __restrict__ bias, float* __restrict__ out, int bid) {
  const int lane = threadIdx.x & 63, wv = threadIdx.x >> 6;
  const int d4 = lane * 4;
#pragma unroll
  for (int rr = 0; rr < 2; rr++) {
    const int i = bid * 8 + wv * 2 + rr;
    float4 pv = make_float4(0.f, 0.f, 0.f, 0.f);
    for (int s = 0; s < nsplit; s++) {
      const float4 t = *(const float4*)(hp + (size_t)s * NN * DD + (size_t)i * DD + d4);
      pv.x += t.x; pv.y += t.y; pv.z += t.z; pv.w += t.w;
    }
    const float4 xv = *(const float4*)(x + (size_t)i * DD + d4);
    float4 v;
    v.x = 0.5f * pv.x + 0.5f * (xv.x * cw + cb);
    v.y = 0.5f * pv.y + 0.5f * (xv.y * cw + cb);
    v.z = 0.5f * pv.z + 0.5f * (xv.z * cw + cb);
    v.w = 0.5f * pv.w + 0.5f * (xv.w * cw + cb);
    v.x = v.x > 0.f ? v.x : expm1f(v.x);
    v.y = v.y > 0.f ? v.y : expm1f(v.y);
    v.z = v.z > 0.f ? v.z : expm1f(v.z);
    v.w = v.w > 0.f ? v.w : expm1f(v.w);
    float ss = v.x * v.x + v.y * v.y + v.z * v.z + v.w * v.w;
#pragma unroll
    for (int off = 32; off; off >>= 1) ss += __shfl_xor(ss, off);
    const float inv = 1.f / fmaxf(sqrtf(ss), 1e-12f);
    const float4 bv = *(const float4*)(bias + d4);
    float4 o;
    o.x = v.x * inv + bv.x;
    o.y = v.y * inv + bv.y;
    o.z = v.z * inv + bv.z;
    o.w = v.w * inv + bv.w;
    *(float4*)(out + (size_t)i * DD + d4) = o;
  }
}

// ================= cooperative mega-kernel =================
__global__ __launch_bounds__(256, 2) void k_mega(
    const float* x, const int* adj, const float* cwp, const float* cbp,
    const float* a, const float* bias, float* out,
    unsigned short* hbfT, float* s1, float* s2, float* s2e, float* Mb,
    unsigned short* Wm, float* hp) {
  __shared__ __align__(16) char smem[40960];
  const float cw = cwp[0], cb = cbp[0];
  const int bid = blockIdx.x;
  cg::grid_group grid = cg::this_grid();
  phase1(x, a, cw, cb, hbfT, s1, s2, s2e, bid, smem);
  grid.sync();
  phase2(s2, Mb, bid, smem);
  grid.sync();
  phase3(adj, s1, s2e, Mb, Wm, bid, smem);
  grid.sync();
  phase4(Wm, hbfT, hp, 1, bid, smem);
  grid.sync();
  phase5(hp, SPLIT, x, cw, cb, bias, out, bid);
}

// ================= fallback: same phases as separate kernels =================
__global__ __launch_bounds__(256) void k_zero(float* __restrict__ hp) {
  int idx = blockIdx.x * 256 + threadIdx.x;
  ((float4*)hp)[idx] = make_float4(0.f, 0.f, 0.f, 0.f);
}
__global__ __launch_bounds__(256, 2) void k_p1(const float* x, const float* a,
                                               const float* cwp, const float* cbp,
                                               unsigned short* hbfT, float* s1,
                                               float* s2, float* s2e) {
  __shared__ __align__(16) char smem[40960];
  phase1(x, a, cwp[0], cbp[0], hbfT, s1, s2, s2e, blockIdx.x, smem);
}
__global__ __launch_bounds__(256, 2) void k_p2(const float* s2, float* Mb) {
  __shared__ __align__(16) char smem[256];
  phase2(s2, Mb, blockIdx.x, smem);
}
__global__ __launch_bounds__(256, 2) void k_p3(const int* adj, const float* s1,
                                               const float* s2e, const float* Mb,
                                               unsigned short* Wm) {
  __shared__ __align__(16) char smem[256];
  phase3(adj, s1, s2e, Mb, Wm, blockIdx.x, smem);
}
__global__ __launch_bounds__(256, 2) void k_p4(const unsigned short* Wm,
                                               const unsigned short* hbfT,
                                               float* hp, int useSplit) {
  __shared__ __align__(16) char smem[40960];
  phase4(Wm, hbfT, hp, useSplit, blockIdx.x, smem);
}
__global__ __launch_bounds__(256, 2) void k_p5(const float* hp, int nsplit,
                                               const float* x, const float* cwp,
                                               const float* cbp, const float* bias,
                                               float* out) {
  phase5(hp, nsplit, x, cwp[0], cbp[0], bias, out, blockIdx.x);
}

extern "C" void kernel_launch(void* const* d_in, const int* in_sizes, int n_in,
                              void* d_out, int out_size, void* d_ws, size_t ws_size,
                              hipStream_t stream) {
  const float* x = (const float*)d_in[0];
  const int* adj = (const int*)d_in[1];
  const float* cw = (const float*)d_in[2];
  const float* cb = (const float*)d_in[3];
  const float* a = (const float*)d_in[4];
  const float* bias = (const float*)d_in[5];
  float* out = (float*)d_out;
  float* ws = (float*)d_ws;

  // layout (float units): s1 | s2 | s2e | Mb | hbfT | Wm | hp
  float* s1 = ws;
  float* s2 = ws + 16384;
  float* s2e = ws + 32768;
  float* Mb = ws + 49152;
  unsigned short* hbfT = (unsigned short*)(ws + 49408);
  unsigned short* Wm = (unsigned short*)(ws + 49408 + 524288);
  float* hp = ws + 49408 + 524288 + 8388608;

  const size_t needSplit =
      (size_t)(49408 + 524288 + 8388608 + (size_t)SPLIT * NN * DD) * 4;
  const int useSplit = (ws_size >= needSplit) ? 1 : 0;
  const int nsplit = useSplit ? SPLIT : 1;

  hipError_t rc = hipErrorUnknown;
  if (useSplit) {
    void* args[] = {(void*)&x,    (void*)&adj, (void*)&cw,   (void*)&cb,
                    (void*)&a,    (void*)&bias, (void*)&out, (void*)&hbfT,
                    (void*)&s1,   (void*)&s2,  (void*)&s2e,  (void*)&Mb,
                    (void*)&Wm,   (void*)&hp};
    rc = hipLaunchCooperativeKernel((void*)k_mega, dim3(NB), dim3(256), args, 0, stream);
  }
  if (rc != hipSuccess) {
    int sp8 = useSplit ? SPLIT : 1;
    if (!useSplit) hipLaunchKernelGGL(k_zero, dim3(1024), dim3(256), 0, stream, hp);
    hipLaunchKernelGGL(k_p1, dim3(NB), dim3(256), 0, stream, x, a, cw, cb, hbfT, s1, s2, s2e);
    hipLaunchKernelGGL(k_p2, dim3(HH), dim3(256), 0, stream, s2, Mb);
    hipLaunchKernelGGL(k_p3, dim3(NB), dim3(256), 0, stream, adj, s1, s2e, Mb, Wm);
    hipLaunchKernelGGL(k_p4, dim3(NB), dim3(256), 0, stream, Wm, hbfT, hp, useSplit);
    hipLaunchKernelGGL(k_p5, dim3(NB), dim3(256), 0, stream, hp, sp8, x, cw, cb, bias, out);
  }
}

// Round 7
// 173.877 us; speedup vs baseline: 2.4263x; 2.4263x over previous
//
#include <hip/hip_runtime.h>
#include <math.h>

#define NN 4096
#define DD 256
#define HH 4
#define SPLIT 8
#define BKG 64

typedef short short8 __attribute__((ext_vector_type(8)));
typedef float float4v __attribute__((ext_vector_type(4)));

__device__ __forceinline__ unsigned short f2bf(float f) {
  unsigned u = __float_as_uint(f);
  u += 0x7FFF + ((u >> 16) & 1);   // RNE
  return (unsigned short)(u >> 16);
}
__device__ __forceinline__ unsigned f2bf_pk(float a, float b) {
  unsigned ua = __float_as_uint(a); ua += 0x7FFF + ((ua >> 16) & 1);
  unsigned ub = __float_as_uint(b); ub += 0x7FFF + ((ub >> 16) & 1);
  return __builtin_amdgcn_perm(ub, ua, 0x07060302);
}
__device__ __forceinline__ unsigned encf(float f) {   // monotone float->uint
  unsigned b = __float_as_uint(f);
  return (b & 0x80000000u) ? ~b : (b | 0x80000000u);
}
__device__ __forceinline__ float decf(unsigned e) {
  unsigned b = (e & 0x80000000u) ? (e & 0x7FFFFFFFu) : ~e;
  return __uint_as_float(b);
}
__device__ __forceinline__ void gld16(void* lds, const void* gp) {
  __builtin_amdgcn_global_load_lds(
      (const __attribute__((address_space(1))) unsigned int*)gp,
      (__attribute__((address_space(3))) unsigned int*)lds, 16, 0, 0);
}

// ---------------- zero hp (atomic fallback only) ----------------
__global__ void k_zero(float* __restrict__ hp) {
  int idx = blockIdx.x * 256 + threadIdx.x;
  ((float4*)hp)[idx] = make_float4(0.f, 0.f, 0.f, 0.f);
}

// ======= k_pre: blocks 0..255 transpose x->hbfT; blocks 256..319 scores + max =======
__global__ __launch_bounds__(256) void k_pre(
    const float* __restrict__ x, const float* __restrict__ a,
    const float* __restrict__ cwp, const float* __restrict__ cbp,
    unsigned short* __restrict__ hbfT, float* __restrict__ s1,
    float* __restrict__ s2e, unsigned* __restrict__ MbEnc) {
  const int tid = threadIdx.x;
  const int bid = blockIdx.x;
  const float cw = cwp[0], cb = cbp[0];

  if (bid < 256) {
    __shared__ float t[64][65];
    const int j0 = (bid & 63) * 64, d0 = (bid >> 6) * 64;
    const int r = tid >> 4, c4 = tid & 15;
#pragma unroll
    for (int p = 0; p < 4; p++) {
      const int jj = p * 16 + r;
      const float4 v = *(const float4*)(x + (size_t)(j0 + jj) * DD + d0 + c4 * 4);
      t[jj][c4 * 4 + 0] = v.x * cw + cb;
      t[jj][c4 * 4 + 1] = v.y * cw + cb;
      t[jj][c4 * 4 + 2] = v.z * cw + cb;
      t[jj][c4 * 4 + 3] = v.w * cw + cb;
    }
    __syncthreads();
    const int jc = (tid & 15) * 4, db = tid >> 4;
#pragma unroll
    for (int p = 0; p < 4; p++) {
      const int dd = p * 16 + db;
      const unsigned l0 = f2bf(t[jc + 0][dd]);
      const unsigned l1 = f2bf(t[jc + 1][dd]);
      const unsigned l2 = f2bf(t[jc + 2][dd]);
      const unsigned l3 = f2bf(t[jc + 3][dd]);
      uint2 val;
      val.x = l0 | (l1 << 16);
      val.y = l2 | (l3 << 16);
      *(uint2*)(hbfT + (size_t)(d0 + dd) * NN + j0 + jc) = val;
    }
  } else {
    __shared__ unsigned mx[HH];
    if (tid < HH) mx[tid] = 0;
    __syncthreads();
    const int ln = tid >> 2, qd = (tid & 3) * 64;
    const int node = (bid - 256) * 64 + ln;
    float p1[HH] = {0.f, 0.f, 0.f, 0.f}, p2[HH] = {0.f, 0.f, 0.f, 0.f};
#pragma unroll
    for (int k = 0; k < 16; k++) {
      const int d = qd + k * 4;
      const float4 v = *(const float4*)(x + (size_t)node * DD + d);
      const float h0 = v.x * cw + cb, h1 = v.y * cw + cb;
      const float h2 = v.z * cw + cb, h3 = v.w * cw + cb;
#pragma unroll
      for (int h = 0; h < HH; h++) {
        const float4 a1 = *(const float4*)(a + h * 512 + d);
        const float4 a2 = *(const float4*)(a + h * 512 + 256 + d);
        p1[h] += h0 * a1.x + h1 * a1.y + h2 * a1.z + h3 * a1.w;
        p2[h] += h0 * a2.x + h1 * a2.y + h2 * a2.z + h3 * a2.w;
      }
    }
#pragma unroll
    for (int off = 1; off <= 2; off <<= 1) {
#pragma unroll
      for (int h = 0; h < HH; h++) {
        p1[h] += __shfl_xor(p1[h], off);
        p2[h] += __shfl_xor(p2[h], off);
      }
    }
    if ((tid & 3) == 0) {
#pragma unroll
      for (int h = 0; h < HH; h++) {
        s1[h * NN + node] = p1[h];
        s2e[h * NN + node] = __expf(p2[h]);
        atomicMax(&mx[h], encf(p2[h]));
      }
    }
    __syncthreads();
    if (tid < HH) atomicMax(&MbEnc[tid], mx[tid]);
  }
}

// ======= k_zw: fused Z + W, P in registers, separable exp =======
__global__ __launch_bounds__(256) void k_zw(
    const int* __restrict__ adj, const float* __restrict__ s1g,
    const float* __restrict__ s2e, const unsigned* __restrict__ MbEnc,
    unsigned short* __restrict__ Wm) {
  __shared__ float red[4][HH];
  __shared__ float sZi[HH];

  const int i = blockIdx.x;
  const int tid = threadIdx.x;
  float Rp[HH], RpRB[HH], Cc[HH], z[HH];
#pragma unroll
  for (int h = 0; h < HH; h++) {
    const float s1v = s1g[h * NN + i];
    const float M = decf(MbEnc[h]);
    const float t = s1v + M;
    const float B = t > 0.f ? t : __expf(t) - 1.f;
    Rp[h] = __expf(s1v);
    RpRB[h] = __expf(s1v - B);
    Cc[h] = __expf(-1.f - B);
    z[h] = 0.f;
  }
  unsigned P[4][HH][2];
  const int4* arow = (const int4*)(adj + (size_t)i * NN);
#pragma unroll
  for (int k = 0; k < 4; k++) {
    const int j4 = tid + k * 256;
    const int4 av = arow[j4];
    const bool m0 = av.x > 0, m1 = av.y > 0, m2 = av.z > 0, m3 = av.w > 0;
#pragma unroll
    for (int h = 0; h < HH; h++) {
      const float4 E = *(const float4*)(s2e + h * NN + j4 * 4);
      float u, p0, p1, p2, p3;
      u = Rp[h] * E.x; p0 = u > 1.f ? RpRB[h] * E.x : Cc[h] * __expf(u);
      u = Rp[h] * E.y; p1 = u > 1.f ? RpRB[h] * E.y : Cc[h] * __expf(u);
      u = Rp[h] * E.z; p2 = u > 1.f ? RpRB[h] * E.z : Cc[h] * __expf(u);
      u = Rp[h] * E.w; p3 = u > 1.f ? RpRB[h] * E.w : Cc[h] * __expf(u);
      p0 = m0 ? p0 : 0.f; p1 = m1 ? p1 : 0.f;
      p2 = m2 ? p2 : 0.f; p3 = m3 ? p3 : 0.f;
      z[h] += (p0 + p1) + (p2 + p3);
      P[k][h][0] = f2bf_pk(p0, p1);
      P[k][h][1] = f2bf_pk(p2, p3);
    }
  }
#pragma unroll
  for (int h = 0; h < HH; h++) {
#pragma unroll
    for (int off = 32; off; off >>= 1) z[h] += __shfl_xor(z[h], off);
  }
  const int lane = tid & 63, wv = tid >> 6;
  if (lane == 0) {
#pragma unroll
    for (int h = 0; h < HH; h++) red[wv][h] = z[h];
  }
  __syncthreads();
  if (tid < HH) {
    const float zt = red[0][tid] + red[1][tid] + red[2][tid] + red[3][tid];
    sZi[tid] = zt > 0.f ? 0.25f / zt : 0.f;
  }
  __syncthreads();
  float Zi[HH];
#pragma unroll
  for (int h = 0; h < HH; h++) Zi[h] = sZi[h];

  unsigned* wrow = (unsigned*)(Wm + (size_t)i * NN);
#pragma unroll
  for (int k = 0; k < 4; k++) {
    const int j4 = tid + k * 256;
    float w0 = 0.f, w1 = 0.f, w2 = 0.f, w3 = 0.f;
#pragma unroll
    for (int h = 0; h < HH; h++) {
      const unsigned pa = P[k][h][0];
      const unsigned pb = P[k][h][1];
      w0 += __uint_as_float(pa << 16) * Zi[h];
      w1 += __uint_as_float(pa & 0xffff0000u) * Zi[h];
      w2 += __uint_as_float(pb << 16) * Zi[h];
      w3 += __uint_as_float(pb & 0xffff0000u) * Zi[h];
    }
    wrow[j4 * 2] = f2bf_pk(w0, w1);
    wrow[j4 * 2 + 1] = f2bf_pk(w2, w3);
  }
}

// ======= k_gemm: m97-style MFMA GEMM, global_load_lds staging, XOR-swizzled LDS =======
// LDS layout: phys slot (row, k8p) holds element (row, j0 + (k8p ^ (row&7))*8)
__global__ __launch_bounds__(256) void k_gemm(
    const unsigned short* __restrict__ Wm, const unsigned short* __restrict__ hbfT,
    float* __restrict__ hpOut, int useSplit) {
  __shared__ __align__(16) unsigned short sA[64 * 64];    // 8 KB  W tile
  __shared__ __align__(16) unsigned short sB[256 * 64];   // 32 KB h^T tile
  const int tid = threadIdx.x;
  const int wv = tid >> 6, lane = tid & 63;
  const int m16 = lane & 15, q = lane >> 4, m7 = m16 & 7;
  const int rb = blockIdx.x >> 3, sp = blockIdx.x & 7;
  const int i0 = rb * 64;
  const int jlo = sp * (NN / SPLIT);
  const int lr = lane >> 3;                 // staging row-within-group
  const int lk8 = (lane & 7) ^ lr;          // swizzled k8 for staging

  float4v acc[4][4];
#pragma unroll
  for (int a = 0; a < 4; a++)
#pragma unroll
    for (int b = 0; b < 4; b++) acc[a][b] = (float4v)0.f;

  for (int kt = 0; kt < (NN / SPLIT) / BKG; kt++) {
    const int j0 = jlo + kt * BKG;
    __syncthreads();
#pragma unroll
    for (int t = 0; t < 2; t++) {
      const int r0 = wv * 16 + t * 8;
      gld16(sA + r0 * 64, Wm + (size_t)(i0 + r0 + lr) * NN + j0 + lk8 * 8);
    }
#pragma unroll
    for (int t = 0; t < 8; t++) {
      const int r0 = wv * 64 + t * 8;
      gld16(sB + r0 * 64, hbfT + (size_t)(r0 + lr) * NN + j0 + lk8 * 8);
    }
    __syncthreads();
#pragma unroll
    for (int ks = 0; ks < 2; ks++) {
      const int kp = ((ks * 4 + q) ^ m7) * 8;   // swizzled fragment column
      short8 aF[4], bF[4];
#pragma unroll
      for (int it = 0; it < 4; it++)
        aF[it] = *(const short8*)(sA + (it * 16 + m16) * 64 + kp);
#pragma unroll
      for (int dt = 0; dt < 4; dt++)
        bF[dt] = *(const short8*)(sB + (wv * 64 + dt * 16 + m16) * 64 + kp);
#pragma unroll
      for (int it = 0; it < 4; it++)
#pragma unroll
        for (int dt = 0; dt < 4; dt++)
          acc[it][dt] = __builtin_amdgcn_mfma_f32_16x16x32_bf16(aF[it], bF[dt], acc[it][dt], 0, 0, 0);
    }
  }

  if (useSplit) {
    float* base = hpOut + (size_t)sp * NN * DD;
#pragma unroll
    for (int it = 0; it < 4; it++)
#pragma unroll
      for (int dt = 0; dt < 4; dt++) {
        const int d = wv * 64 + dt * 16 + m16;
#pragma unroll
        for (int rg = 0; rg < 4; rg++)
          base[(size_t)(i0 + it * 16 + q * 4 + rg) * DD + d] = acc[it][dt][rg];
      }
  } else {
#pragma unroll
    for (int it = 0; it < 4; it++)
#pragma unroll
      for (int dt = 0; dt < 4; dt++) {
        const int d = wv * 64 + dt * 16 + m16;
#pragma unroll
        for (int rg = 0; rg < 4; rg++)
          atomicAdd(&hpOut[(size_t)(i0 + it * 16 + q * 4 + rg) * DD + d], acc[it][dt][rg]);
      }
  }
}

// ---------------- k_epi ----------------
__global__ __launch_bounds__(256) void k_epi(
    const float* __restrict__ hp, int nsplit, const float* __restrict__ x,
    const float* __restrict__ cwp, const float* __restrict__ cbp,
    const float* __restrict__ bias, float* __restrict__ out) {
  const int lane = threadIdx.x & 63, wv = threadIdx.x >> 6;
  const int i = blockIdx.x * 4 + wv;
  const float cw = cwp[0], cb = cbp[0];
  const int d4 = lane * 4;
  float4 pv = make_float4(0.f, 0.f, 0.f, 0.f);
  for (int s = 0; s < nsplit; s++) {
    const float4 t = *(const float4*)(hp + (size_t)s * NN * DD + (size_t)i * DD + d4);
    pv.x += t.x; pv.y += t.y; pv.z += t.z; pv.w += t.w;
  }
  const float4 xv = *(const float4*)(x + (size_t)i * DD + d4);
  float4 v;
  v.x = 0.5f * pv.x + 0.5f * (xv.x * cw + cb);
  v.y = 0.5f * pv.y + 0.5f * (xv.y * cw + cb);
  v.z = 0.5f * pv.z + 0.5f * (xv.z * cw + cb);
  v.w = 0.5f * pv.w + 0.5f * (xv.w * cw + cb);
  v.x = v.x > 0.f ? v.x : expm1f(v.x);
  v.y = v.y > 0.f ? v.y : expm1f(v.y);
  v.z = v.z > 0.f ? v.z : expm1f(v.z);
  v.w = v.w > 0.f ? v.w : expm1f(v.w);
  float ss = v.x * v.x + v.y * v.y + v.z * v.z + v.w * v.w;
#pragma unroll
  for (int off = 32; off; off >>= 1) ss += __shfl_xor(ss, off);
  const float inv = 1.f / fmaxf(sqrtf(ss), 1e-12f);
  const float4 bv = *(const float4*)(bias + d4);
  float4 o;
  o.x = v.x * inv + bv.x;
  o.y = v.y * inv + bv.y;
  o.z = v.z * inv + bv.z;
  o.w = v.w * inv + bv.w;
  *(float4*)(out + (size_t)i * DD + d4) = o;
}

extern "C" void kernel_launch(void* const* d_in, const int* in_sizes, int n_in,
                              void* d_out, int out_size, void* d_ws, size_t ws_size,
                              hipStream_t stream) {
  const float* x = (const float*)d_in[0];
  const int* adj = (const int*)d_in[1];
  const float* cw = (const float*)d_in[2];
  const float* cb = (const float*)d_in[3];
  const float* a = (const float*)d_in[4];
  const float* bias = (const float*)d_in[5];
  float* out = (float*)d_out;
  float* ws = (float*)d_ws;

  // layout (float units): s1 | s2e | MbEnc | hbfT | Wm | hp
  float* s1 = ws;                                       // 16384
  float* s2e = ws + 16384;                              // 16384
  unsigned* MbEnc = (unsigned*)(ws + 32768);            // 64 (padded 256)
  unsigned short* hbfT = (unsigned short*)(ws + 33024); // 1M shorts = 524288 f
  unsigned short* Wm = (unsigned short*)(ws + 33024 + 524288);  // 16M shorts
  float* hp = ws + 33024 + 524288 + 8388608;            // SPLIT * N * D

  const size_t needSplit =
      (size_t)(33024 + 524288 + 8388608 + (size_t)SPLIT * NN * DD) * 4;
  const int useSplit = (ws_size >= needSplit) ? 1 : 0;
  const int nsplit = useSplit ? SPLIT : 1;

  hipMemsetAsync(MbEnc, 0, HH * sizeof(unsigned), stream);
  if (!useSplit) hipLaunchKernelGGL(k_zero, dim3(1024), dim3(256), 0, stream, hp);
  hipLaunchKernelGGL(k_pre, dim3(320), dim3(256), 0, stream, x, a, cw, cb, hbfT, s1, s2e, MbEnc);
  hipLaunchKernelGGL(k_zw, dim3(NN), dim3(256), 0, stream, adj, s1, s2e, MbEnc, Wm);
  hipLaunchKernelGGL(k_gemm, dim3(64 * SPLIT), dim3(256), 0, stream, Wm, hbfT, hp, useSplit);
  hipLaunchKernelGGL(k_epi, dim3(1024), dim3(256), 0, stream, hp, nsplit, x, cw, cb, bias, out);
}

// Round 8
// 167.581 us; speedup vs baseline: 2.5175x; 1.0376x over previous
//
#include <hip/hip_runtime.h>
#include <math.h>

#define NN 4096
#define DD 256
#define HH 4
#define SPLIT 8
#define BKG 64

typedef short short8 __attribute__((ext_vector_type(8)));
typedef float float4v __attribute__((ext_vector_type(4)));

__device__ __forceinline__ unsigned short f2bf(float f) {
  unsigned u = __float_as_uint(f);
  u += 0x7FFF + ((u >> 16) & 1);   // RNE
  return (unsigned short)(u >> 16);
}
__device__ __forceinline__ unsigned f2bf_pk(float a, float b) {
  unsigned ua = __float_as_uint(a); ua += 0x7FFF + ((ua >> 16) & 1);
  unsigned ub = __float_as_uint(b); ub += 0x7FFF + ((ub >> 16) & 1);
  return __builtin_amdgcn_perm(ub, ua, 0x07060302);
}
__device__ __forceinline__ void gld16(void* lds, const void* gp) {
  __builtin_amdgcn_global_load_lds(
      (const __attribute__((address_space(1))) unsigned int*)gp,
      (__attribute__((address_space(3))) unsigned int*)lds, 16, 0, 0);
}

// ---------------- zero hp (atomic fallback only) ----------------
__global__ void k_zero(float* __restrict__ hp) {
  int idx = blockIdx.x * 256 + threadIdx.x;
  ((float4*)hp)[idx] = make_float4(0.f, 0.f, 0.f, 0.f);
}

// ======= k_pre: blocks 0..255 transpose x->hbfT; blocks 256..319 scores =======
// Rp[h][i] = exp(s1), Ebf[h][j] = bf16(exp(s2)); no max pass (unshifted softmax
// is safe: e <= s1+s2 < ~40, exp(40)=2e17 << fp32 max)
__global__ __launch_bounds__(256) void k_pre(
    const float* __restrict__ x, const float* __restrict__ a,
    const float* __restrict__ cwp, const float* __restrict__ cbp,
    unsigned short* __restrict__ hbfT, float* __restrict__ Rpg,
    unsigned short* __restrict__ Ebf) {
  const int tid = threadIdx.x;
  const int bid = blockIdx.x;
  const float cw = cwp[0], cb = cbp[0];

  if (bid < 256) {
    __shared__ float t[64][65];
    const int j0 = (bid & 63) * 64, d0 = (bid >> 6) * 64;
    const int r = tid >> 4, c4 = tid & 15;
#pragma unroll
    for (int p = 0; p < 4; p++) {
      const int jj = p * 16 + r;
      const float4 v = *(const float4*)(x + (size_t)(j0 + jj) * DD + d0 + c4 * 4);
      t[jj][c4 * 4 + 0] = v.x * cw + cb;
      t[jj][c4 * 4 + 1] = v.y * cw + cb;
      t[jj][c4 * 4 + 2] = v.z * cw + cb;
      t[jj][c4 * 4 + 3] = v.w * cw + cb;
    }
    __syncthreads();
    const int jc = (tid & 15) * 4, db = tid >> 4;
#pragma unroll
    for (int p = 0; p < 4; p++) {
      const int dd = p * 16 + db;
      const unsigned l0 = f2bf(t[jc + 0][dd]);
      const unsigned l1 = f2bf(t[jc + 1][dd]);
      const unsigned l2 = f2bf(t[jc + 2][dd]);
      const unsigned l3 = f2bf(t[jc + 3][dd]);
      uint2 val;
      val.x = l0 | (l1 << 16);
      val.y = l2 | (l3 << 16);
      *(uint2*)(hbfT + (size_t)(d0 + dd) * NN + j0 + jc) = val;
    }
  } else {
    const int ln = tid >> 2, qd = (tid & 3) * 64;
    const int node = (bid - 256) * 64 + ln;
    float p1[HH] = {0.f, 0.f, 0.f, 0.f}, p2[HH] = {0.f, 0.f, 0.f, 0.f};
#pragma unroll
    for (int k = 0; k < 16; k++) {
      const int d = qd + k * 4;
      const float4 v = *(const float4*)(x + (size_t)node * DD + d);
      const float h0 = v.x * cw + cb, h1 = v.y * cw + cb;
      const float h2 = v.z * cw + cb, h3 = v.w * cw + cb;
#pragma unroll
      for (int h = 0; h < HH; h++) {
        const float4 a1 = *(const float4*)(a + h * 512 + d);
        const float4 a2 = *(const float4*)(a + h * 512 + 256 + d);
        p1[h] += h0 * a1.x + h1 * a1.y + h2 * a1.z + h3 * a1.w;
        p2[h] += h0 * a2.x + h1 * a2.y + h2 * a2.z + h3 * a2.w;
      }
    }
#pragma unroll
    for (int off = 1; off <= 2; off <<= 1) {
#pragma unroll
      for (int h = 0; h < HH; h++) {
        p1[h] += __shfl_xor(p1[h], off);
        p2[h] += __shfl_xor(p2[h], off);
      }
    }
    if ((tid & 3) == 0) {
#pragma unroll
      for (int h = 0; h < HH; h++) {
        Rpg[h * NN + node] = __expf(p1[h]);
        Ebf[h * NN + node] = f2bf(__expf(p2[h]));
      }
    }
  }
}

// ======= k_zw: fused Z + W, unshifted softmax, bf16 E, P in registers =======
__global__ __launch_bounds__(256) void k_zw(
    const int* __restrict__ adj, const float* __restrict__ Rpg,
    const unsigned short* __restrict__ Ebf, unsigned short* __restrict__ Wm) {
  __shared__ float red[4][HH];
  __shared__ float sZi[HH];

  const int i = blockIdx.x;
  const int tid = threadIdx.x;
  const float C = 0.36787944117144233f;   // e^-1
  float Rp[HH], z[HH];
#pragma unroll
  for (int h = 0; h < HH; h++) {
    Rp[h] = Rpg[h * NN + i];
    z[h] = 0.f;
  }
  unsigned P[4][HH][2];
  const int4* arow = (const int4*)(adj + (size_t)i * NN);
#pragma unroll
  for (int k = 0; k < 4; k++) {
    const int j4 = tid + k * 256;
    const int4 av = arow[j4];
    const bool m0 = av.x > 0, m1 = av.y > 0, m2 = av.z > 0, m3 = av.w > 0;
#pragma unroll
    for (int h = 0; h < HH; h++) {
      const uint2 e2 = *(const uint2*)(Ebf + (size_t)h * NN + j4 * 4);
      const float E0 = __uint_as_float(e2.x << 16);
      const float E1 = __uint_as_float(e2.x & 0xffff0000u);
      const float E2 = __uint_as_float(e2.y << 16);
      const float E3 = __uint_as_float(e2.y & 0xffff0000u);
      float u, p0, p1, p2, p3;
      u = Rp[h] * E0; p0 = u > 1.f ? u : C * __expf(u);
      p0 = m0 ? p0 : 0.f;
      u = Rp[h] * E1; p1 = u > 1.f ? u : C * __expf(u);
      p1 = m1 ? p1 : 0.f;
      u = Rp[h] * E2; p2 = u > 1.f ? u : C * __expf(u);
      p2 = m2 ? p2 : 0.f;
      u = Rp[h] * E3; p3 = u > 1.f ? u : C * __expf(u);
      p3 = m3 ? p3 : 0.f;
      z[h] += (p0 + p1) + (p2 + p3);
      P[k][h][0] = f2bf_pk(p0, p1);
      P[k][h][1] = f2bf_pk(p2, p3);
    }
  }
#pragma unroll
  for (int h = 0; h < HH; h++) {
#pragma unroll
    for (int off = 32; off; off >>= 1) z[h] += __shfl_xor(z[h], off);
  }
  const int lane = tid & 63, wv = tid >> 6;
  if (lane == 0) {
#pragma unroll
    for (int h = 0; h < HH; h++) red[wv][h] = z[h];
  }
  __syncthreads();
  if (tid < HH) {
    const float zt = red[0][tid] + red[1][tid] + red[2][tid] + red[3][tid];
    sZi[tid] = zt > 0.f ? 0.25f / zt : 0.f;
  }
  __syncthreads();
  float Zi[HH];
#pragma unroll
  for (int h = 0; h < HH; h++) Zi[h] = sZi[h];

  unsigned* wrow = (unsigned*)(Wm + (size_t)i * NN);
#pragma unroll
  for (int k = 0; k < 4; k++) {
    const int j4 = tid + k * 256;
    float w0 = 0.f, w1 = 0.f, w2 = 0.f, w3 = 0.f;
#pragma unroll
    for (int h = 0; h < HH; h++) {
      const unsigned pa = P[k][h][0];
      const unsigned pb = P[k][h][1];
      w0 += __uint_as_float(pa << 16) * Zi[h];
      w1 += __uint_as_float(pa & 0xffff0000u) * Zi[h];
      w2 += __uint_as_float(pb << 16) * Zi[h];
      w3 += __uint_as_float(pb & 0xffff0000u) * Zi[h];
    }
    wrow[j4 * 2] = f2bf_pk(w0, w1);
    wrow[j4 * 2 + 1] = f2bf_pk(w2, w3);
  }
}

// ======= k_gemm: MFMA GEMM, global_load_lds staging, XOR-swizzled LDS =======
__global__ __launch_bounds__(256) void k_gemm(
    const unsigned short* __restrict__ Wm, const unsigned short* __restrict__ hbfT,
    float* __restrict__ hpOut, int useSplit) {
  __shared__ __align__(16) unsigned short sA[64 * 64];    // 8 KB  W tile
  __shared__ __align__(16) unsigned short sB[256 * 64];   // 32 KB h^T tile
  const int tid = threadIdx.x;
  const int wv = tid >> 6, lane = tid & 63;
  const int m16 = lane & 15, q = lane >> 4, m7 = m16 & 7;
  const int rb = blockIdx.x >> 3, sp = blockIdx.x & 7;
  const int i0 = rb * 64;
  const int jlo = sp * (NN / SPLIT);
  const int lr = lane >> 3;
  const int lk8 = (lane & 7) ^ lr;

  float4v acc[4][4];
#pragma unroll
  for (int a = 0; a < 4; a++)
#pragma unroll
    for (int b = 0; b < 4; b++) acc[a][b] = (float4v)0.f;

  for (int kt = 0; kt < (NN / SPLIT) / BKG; kt++) {
    const int j0 = jlo + kt * BKG;
    __syncthreads();
#pragma unroll
    for (int t = 0; t < 2; t++) {
      const int r0 = wv * 16 + t * 8;
      gld16(sA + r0 * 64, Wm + (size_t)(i0 + r0 + lr) * NN + j0 + lk8 * 8);
    }
#pragma unroll
    for (int t = 0; t < 8; t++) {
      const int r0 = wv * 64 + t * 8;
      gld16(sB + r0 * 64, hbfT + (size_t)(r0 + lr) * NN + j0 + lk8 * 8);
    }
    __syncthreads();
#pragma unroll
    for (int ks = 0; ks < 2; ks++) {
      const int kp = ((ks * 4 + q) ^ m7) * 8;
      short8 aF[4], bF[4];
#pragma unroll
      for (int it = 0; it < 4; it++)
        aF[it] = *(const short8*)(sA + (it * 16 + m16) * 64 + kp);
#pragma unroll
      for (int dt = 0; dt < 4; dt++)
        bF[dt] = *(const short8*)(sB + (wv * 64 + dt * 16 + m16) * 64 + kp);
#pragma unroll
      for (int it = 0; it < 4; it++)
#pragma unroll
        for (int dt = 0; dt < 4; dt++)
          acc[it][dt] = __builtin_amdgcn_mfma_f32_16x16x32_bf16(aF[it], bF[dt], acc[it][dt], 0, 0, 0);
    }
  }

  if (useSplit) {
    float* base = hpOut + (size_t)sp * NN * DD;
#pragma unroll
    for (int it = 0; it < 4; it++)
#pragma unroll
      for (int dt = 0; dt < 4; dt++) {
        const int d = wv * 64 + dt * 16 + m16;
#pragma unroll
        for (int rg = 0; rg < 4; rg++)
          base[(size_t)(i0 + it * 16 + q * 4 + rg) * DD + d] = acc[it][dt][rg];
      }
  } else {
#pragma unroll
    for (int it = 0; it < 4; it++)
#pragma unroll
      for (int dt = 0; dt < 4; dt++) {
        const int d = wv * 64 + dt * 16 + m16;
#pragma unroll
        for (int rg = 0; rg < 4; rg++)
          atomicAdd(&hpOut[(size_t)(i0 + it * 16 + q * 4 + rg) * DD + d], acc[it][dt][rg]);
      }
  }
}

// ---------------- k_epi ----------------
__global__ __launch_bounds__(256) void k_epi(
    const float* __restrict__ hp, int nsplit, const float* __restrict__ x,
    const float* __restrict__ cwp, const float* __restrict__ cbp,
    const float* __restrict__ bias, float* __restrict__ out) {
  const int lane = threadIdx.x & 63, wv = threadIdx.x >> 6;
  const int i = blockIdx.x * 4 + wv;
  const float cw = cwp[0], cb = cbp[0];
  const int d4 = lane * 4;
  float4 pv = make_float4(0.f, 0.f, 0.f, 0.f);
  for (int s = 0; s < nsplit; s++) {
    const float4 t = *(const float4*)(hp + (size_t)s * NN * DD + (size_t)i * DD + d4);
    pv.x += t.x; pv.y += t.y; pv.z += t.z; pv.w += t.w;
  }
  const float4 xv = *(const float4*)(x + (size_t)i * DD + d4);
  float4 v;
  v.x = 0.5f * pv.x + 0.5f * (xv.x * cw + cb);
  v.y = 0.5f * pv.y + 0.5f * (xv.y * cw + cb);
  v.z = 0.5f * pv.z + 0.5f * (xv.z * cw + cb);
  v.w = 0.5f * pv.w + 0.5f * (xv.w * cw + cb);
  v.x = v.x > 0.f ? v.x : expm1f(v.x);
  v.y = v.y > 0.f ? v.y : expm1f(v.y);
  v.z = v.z > 0.f ? v.z : expm1f(v.z);
  v.w = v.w > 0.f ? v.w : expm1f(v.w);
  float ss = v.x * v.x + v.y * v.y + v.z * v.z + v.w * v.w;
#pragma unroll
  for (int off = 32; off; off >>= 1) ss += __shfl_xor(ss, off);
  const float inv = 1.f / fmaxf(sqrtf(ss), 1e-12f);
  const float4 bv = *(const float4*)(bias + d4);
  float4 o;
  o.x = v.x * inv + bv.x;
  o.y = v.y * inv + bv.y;
  o.z = v.z * inv + bv.z;
  o.w = v.w * inv + bv.w;
  *(float4*)(out + (size_t)i * DD + d4) = o;
}

extern "C" void kernel_launch(void* const* d_in, const int* in_sizes, int n_in,
                              void* d_out, int out_size, void* d_ws, size_t ws_size,
                              hipStream_t stream) {
  const float* x = (const float*)d_in[0];
  const int* adj = (const int*)d_in[1];
  const float* cw = (const float*)d_in[2];
  const float* cb = (const float*)d_in[3];
  const float* a = (const float*)d_in[4];
  const float* bias = (const float*)d_in[5];
  float* out = (float*)d_out;
  float* ws = (float*)d_ws;

  // layout (float units): Rpg | Ebf | hbfT | Wm | hp
  float* Rpg = ws;                                        // 16384 floats
  unsigned short* Ebf = (unsigned short*)(ws + 16384);    // 16384 shorts = 8192 f
  unsigned short* hbfT = (unsigned short*)(ws + 24576);   // 1M shorts = 524288 f
  unsigned short* Wm = (unsigned short*)(ws + 24576 + 524288);  // 16M shorts
  float* hp = ws + 24576 + 524288 + 8388608;              // SPLIT * N * D

  const size_t needSplit =
      (size_t)(24576 + 524288 + 8388608 + (size_t)SPLIT * NN * DD) * 4;
  const int useSplit = (ws_size >= needSplit) ? 1 : 0;
  const int nsplit = useSplit ? SPLIT : 1;

  if (!useSplit) hipLaunchKernelGGL(k_zero, dim3(1024), dim3(256), 0, stream, hp);
  hipLaunchKernelGGL(k_pre, dim3(320), dim3(256), 0, stream, x, a, cw, cb, hbfT, Rpg, Ebf);
  hipLaunchKernelGGL(k_zw, dim3(NN), dim3(256), 0, stream, adj, Rpg, Ebf, Wm);
  hipLaunchKernelGGL(k_gemm, dim3(64 * SPLIT), dim3(256), 0, stream, Wm, hbfT, hp, useSplit);
  hipLaunchKernelGGL(k_epi, dim3(1024), dim3(256), 0, stream, hp, nsplit, x, cw, cb, bias, out);
}